// Round 1
// baseline (1074.638 us; speedup 1.0000x reference)
//
#include <hip/hip_runtime.h>
#include <hip/hip_bf16.h>
#include <stdint.h>

#define NE 14
#define NN 10000
#define ED 128
#define KE 1536
#define KH 1792
#define NB 8192

typedef __attribute__((ext_vector_type(4))) float f32x4;
typedef __attribute__((ext_vector_type(8))) short s16x8;

__device__ __forceinline__ short f2bf(float f) {
  union { float f; uint32_t u; } v; v.f = f;
  uint32_t r = (v.u + 0x7fffu + ((v.u >> 16) & 1u)) >> 16;  // RNE
  return (short)r;
}

// ---------------- prep: fp32 [K][N] -> bf16 [N][K] (W_edge per-type + W_het) ----
__global__ __launch_bounds__(256) void prep_transpose(
    const float* __restrict__ We, const float* __restrict__ Wh,
    short* __restrict__ WtE, short* __restrict__ WtH) {
  __shared__ float tile[64][65];
  int b = blockIdx.x;
  int t = threadIdx.x;
  const float* src; short* dst; int K; int kt, nt;
  if (b < NE * 48) {            // 14 types x (1536/64) x (128/64) tiles
    int e = b / 48; int r = b % 48;
    kt = r >> 1; nt = r & 1;
    src = We + (size_t)e * KE * ED;
    dst = WtE + (size_t)e * ED * KE;
    K = KE;
  } else {                      // W_het: (1792/64) x 2 tiles
    int r = b - NE * 48;
    kt = r >> 1; nt = r & 1;
    src = Wh; dst = WtH; K = KH;
  }
  int k0 = kt * 64, n0 = nt * 64;
  for (int i = 0; i < 16; i++) {
    int idx = i * 256 + t;
    int kk = idx >> 6, nn = idx & 63;
    tile[kk][nn] = src[(size_t)(k0 + kk) * ED + n0 + nn];
  }
  __syncthreads();
  for (int i = 0; i < 16; i++) {
    int idx = i * 256 + t;
    int nn = idx >> 6, kk = idx & 63;
    dst[(size_t)(n0 + nn) * K + k0 + kk] = f2bf(tile[kk][nn]);
  }
}

// ---------------- stage1: gather + (8192x1536)@(1536x128) per edge type --------
// grid (64, 14), block 256. Tile BM=128 BN=128 BK=64. XOR-swizzled LDS.
__global__ __launch_bounds__(256) void stage1(
    const float* __restrict__ feat, const short* __restrict__ WtE,
    const float* __restrict__ b_edge, const int* __restrict__ gid,
    short* __restrict__ agg) {
  __shared__ short Alds[128 * 64];
  __shared__ short Blds[128 * 64];
  int t = threadIdx.x;
  int e = blockIdx.y;
  int m0 = blockIdx.x * 128;

  int rowA = t >> 3;   // 0..31
  int cA = t & 7;      // 16B chunk within 64-wide k tile
  const float* baseA[4];
  for (int i = 0; i < 4; i++) {
    int g = gid[m0 + rowA + 32 * i];
    baseA[i] = feat + ((size_t)e * NN + (size_t)g) * KE;
  }
  const short* baseB = WtE + (size_t)e * ED * KE;

  int lane = t & 63;
  int wave = t >> 6;
  int wm = wave >> 1, wn = wave & 1;
  int quad = lane >> 4, l16 = lane & 15;

  f32x4 zero = {0.f, 0.f, 0.f, 0.f};
  f32x4 acc[4][4];
  for (int i = 0; i < 4; i++) for (int j = 0; j < 4; j++) acc[i][j] = zero;

  for (int k0 = 0; k0 < KE; k0 += 64) {
    // stage A (gather rows, fp32 -> bf16)
    for (int i = 0; i < 4; i++) {
      const float* p = baseA[i] + k0 + cA * 8;
      f32x4 x0 = *(const f32x4*)p;
      f32x4 x1 = *(const f32x4*)(p + 4);
      s16x8 v;
      v[0] = f2bf(x0[0]); v[1] = f2bf(x0[1]); v[2] = f2bf(x0[2]); v[3] = f2bf(x0[3]);
      v[4] = f2bf(x1[0]); v[5] = f2bf(x1[1]); v[6] = f2bf(x1[2]); v[7] = f2bf(x1[3]);
      int m = rowA + 32 * i;
      *(s16x8*)&Alds[m * 64 + ((cA ^ (m & 7)) << 3)] = v;
    }
    // stage B (already bf16, [n][k] contiguous)
    for (int i = 0; i < 4; i++) {
      int n = rowA + 32 * i;
      s16x8 v = *(const s16x8*)(baseB + (size_t)n * KE + k0 + cA * 8);
      *(s16x8*)&Blds[n * 64 + ((cA ^ (n & 7)) << 3)] = v;
    }
    __syncthreads();
    for (int ks = 0; ks < 2; ks++) {
      s16x8 af[4], bfr[4];
      for (int mt = 0; mt < 4; mt++) {
        int m = wm * 64 + mt * 16 + l16;
        af[mt] = *(const s16x8*)&Alds[m * 64 + (((ks * 4 + quad) ^ (m & 7)) << 3)];
      }
      for (int nt = 0; nt < 4; nt++) {
        int n = wn * 64 + nt * 16 + l16;
        bfr[nt] = *(const s16x8*)&Blds[n * 64 + (((ks * 4 + quad) ^ (n & 7)) << 3)];
      }
      for (int mt = 0; mt < 4; mt++)
        for (int nt = 0; nt < 4; nt++)
          acc[mt][nt] = __builtin_amdgcn_mfma_f32_16x16x32_bf16(af[mt], bfr[nt], acc[mt][nt], 0, 0, 0);
    }
    __syncthreads();
  }

  // epilogue: bias + leaky_relu -> bf16 agg[b][e*128+n]
  float bias[4];
  for (int nt = 0; nt < 4; nt++) bias[nt] = b_edge[e * ED + wn * 64 + nt * 16 + l16];
  for (int mt = 0; mt < 4; mt++) {
    int mg = m0 + wm * 64 + mt * 16 + quad * 4;
    for (int nt = 0; nt < 4; nt++) {
      int ng = e * ED + wn * 64 + nt * 16 + l16;
      for (int r = 0; r < 4; r++) {
        float v = acc[mt][nt][r] + bias[nt];
        v = v > 0.f ? v : 0.01f * v;
        agg[(size_t)(mg + r) * KH + ng] = f2bf(v);
      }
    }
  }
}

// ---------------- stage2: (8192x1792)@(1792x128) + bias + leaky -> fp32 out ----
// grid 256, block 256. BM=32 BN=128 BK=64.
__global__ __launch_bounds__(256) void stage2(
    const short* __restrict__ agg, const short* __restrict__ WtH,
    const float* __restrict__ b_het, float* __restrict__ out) {
  __shared__ short Alds[32 * 64];
  __shared__ short Blds[128 * 64];
  int t = threadIdx.x;
  int m0 = blockIdx.x * 32;
  int rowA = t >> 3, cA = t & 7;
  int lane = t & 63, wave = t >> 6;
  int wm = wave & 1, wn = wave >> 1;
  int quad = lane >> 4, l16 = lane & 15;

  f32x4 zero = {0.f, 0.f, 0.f, 0.f};
  f32x4 acc[4];
  for (int i = 0; i < 4; i++) acc[i] = zero;

  for (int k0 = 0; k0 < KH; k0 += 64) {
    {
      s16x8 v = *(const s16x8*)(agg + (size_t)(m0 + rowA) * KH + k0 + cA * 8);
      *(s16x8*)&Alds[rowA * 64 + ((cA ^ (rowA & 7)) << 3)] = v;
    }
    for (int i = 0; i < 4; i++) {
      int n = rowA + 32 * i;
      s16x8 v = *(const s16x8*)(WtH + (size_t)n * KH + k0 + cA * 8);
      *(s16x8*)&Blds[n * 64 + ((cA ^ (n & 7)) << 3)] = v;
    }
    __syncthreads();
    for (int ks = 0; ks < 2; ks++) {
      int m = wm * 16 + l16;
      s16x8 a = *(const s16x8*)&Alds[m * 64 + (((ks * 4 + quad) ^ (m & 7)) << 3)];
      for (int nt = 0; nt < 4; nt++) {
        int n = wn * 64 + nt * 16 + l16;
        s16x8 b = *(const s16x8*)&Blds[n * 64 + (((ks * 4 + quad) ^ (n & 7)) << 3)];
        acc[nt] = __builtin_amdgcn_mfma_f32_16x16x32_bf16(a, b, acc[nt], 0, 0, 0);
      }
    }
    __syncthreads();
  }

  for (int nt = 0; nt < 4; nt++) {
    int ng = wn * 64 + nt * 16 + l16;
    float bias = b_het[ng];
    for (int r = 0; r < 4; r++) {
      float v = acc[nt][r] + bias;
      v = v > 0.f ? v : 0.01f * v;
      out[(size_t)(m0 + wm * 16 + quad * 4 + r) * ED + ng] = v;
    }
  }
}

extern "C" void kernel_launch(void* const* d_in, const int* in_sizes, int n_in,
                              void* d_out, int out_size, void* d_ws, size_t ws_size,
                              hipStream_t stream) {
  const float* feat = (const float*)d_in[0];
  const float* We   = (const float*)d_in[1];
  const float* be   = (const float*)d_in[2];
  const float* Wh   = (const float*)d_in[3];
  const float* bh   = (const float*)d_in[4];
  const int*   gid  = (const int*)d_in[5];
  float* out = (float*)d_out;

  char* ws = (char*)d_ws;
  short* WtE = (short*)ws;                                   // 14*128*1536*2 = 5,505,024 B
  short* WtH = (short*)(ws + 5505024);                       // 128*1792*2   =   458,752 B
  short* agg = (short*)(ws + 5505024 + 458752);              // 8192*1792*2  = 29,360,128 B

  prep_transpose<<<NE * 48 + 56, 256, 0, stream>>>(We, Wh, WtE, WtH);
  dim3 g1(NB / 128, NE);
  stage1<<<g1, 256, 0, stream>>>(feat, WtE, be, gid, agg);
  stage2<<<NB / 32, 256, 0, stream>>>(agg, WtH, bh, out);
}